// Round 1
// baseline (1422.136 us; speedup 1.0000x reference)
//
#include <hip/hip_runtime.h>
#include <hip/hip_bf16.h>

#define BATCH 8192

// ---------------- transpose: x f32 [B][3072] -> X0 f32 [3072][B] ----------------
__global__ __launch_bounds__(256) void kT(const float* __restrict__ x, float* __restrict__ X0) {
    __shared__ float t[64][65];
    int tx = threadIdx.x & 63, ty = threadIdx.x >> 6;
    int c0 = blockIdx.x * 64, b0 = blockIdx.y * 64;
#pragma unroll
    for (int r = 0; r < 16; ++r) {
        int i = ty + 4 * r;  // b offset within tile
        t[tx][i] = x[(size_t)(b0 + i) * 3072 + c0 + tx];
    }
    __syncthreads();
#pragma unroll
    for (int r = 0; r < 16; ++r) {
        int i = ty + 4 * r;  // c offset within tile
        X0[(size_t)(c0 + i) * BATCH + b0 + tx] = t[i][tx];
    }
}

// ---------------- conv1: X0 f32 [3][32][32][B] -> A1 bf16 [10][28][28][B] ----------------
__global__ __launch_bounds__(256) void kC1(const float* __restrict__ X0, const float* __restrict__ w,
                                           const float* __restrict__ bias, __hip_bfloat16* __restrict__ A1) {
    __shared__ float ws[750];
    __shared__ float bs[10];
    int tid = threadIdx.x;
    for (int i = tid; i < 750; i += 256) ws[i] = w[i];
    if (tid < 10) bs[tid] = bias[tid];
    __syncthreads();
    int lane = tid & 63, g = tid >> 6;
    int b = blockIdx.x * 64 + lane;
    int oh = blockIdx.y;
    int ow0 = g * 7;
    float acc[10][7];
#pragma unroll
    for (int co = 0; co < 10; ++co)
#pragma unroll
        for (int j = 0; j < 7; ++j) acc[co][j] = bs[co];
    for (int c = 0; c < 3; ++c) {
        for (int kh = 0; kh < 5; ++kh) {
            int ih = oh + kh;
            float xv[11];
#pragma unroll
            for (int i = 0; i < 11; ++i)
                xv[i] = X0[(size_t)((c * 32 + ih) * 32 + ow0 + i) * BATCH + b];
#pragma unroll
            for (int kw = 0; kw < 5; ++kw) {
#pragma unroll
                for (int co = 0; co < 10; ++co) {
                    float wv = ws[((co * 3 + c) * 5 + kh) * 5 + kw];
#pragma unroll
                    for (int j = 0; j < 7; ++j) acc[co][j] += wv * xv[kw + j];
                }
            }
        }
    }
#pragma unroll
    for (int co = 0; co < 10; ++co)
#pragma unroll
        for (int j = 0; j < 7; ++j)
            A1[(size_t)((co * 28 + oh) * 28 + ow0 + j) * BATCH + b] = __float2bfloat16(acc[co][j]);
}

// ---------------- conv2 + 2x2 maxpool: A1 bf16 [10][28][28][B] -> P f32 [20][12][12][B] ----------------
__global__ __launch_bounds__(256, 2) void kC2(const __hip_bfloat16* __restrict__ A1, const float* __restrict__ w,
                                              const float* __restrict__ bias, float* __restrict__ P) {
    __shared__ float ws[5000];
    __shared__ float bs[20];
    int tid = threadIdx.x;
    for (int i = tid; i < 5000; i += 256) ws[i] = w[i];
    if (tid < 20) bs[tid] = bias[tid];
    __syncthreads();
    int lane = tid & 63, g = tid >> 6;
    int b = blockIdx.x * 64 + lane;
    int poh = blockIdx.y;
    int co0 = g * 5;
    for (int h = 0; h < 2; ++h) {  // halves of the output row (12 conv cols each)
        int ow0 = h * 12;
        float res[5][6];
#pragma unroll
        for (int i = 0; i < 5; ++i)
#pragma unroll
            for (int j = 0; j < 6; ++j) res[i][j] = -1e30f;
        for (int r = 0; r < 2; ++r) {  // the two conv rows feeding this pooled row
            int oh = 2 * poh + r;
            float acc[5][12];
#pragma unroll
            for (int i = 0; i < 5; ++i)
#pragma unroll
                for (int j = 0; j < 12; ++j) acc[i][j] = bs[co0 + i];
            for (int c = 0; c < 10; ++c) {
                for (int kh = 0; kh < 5; ++kh) {
                    int ih = oh + kh;
                    float xv[16];
#pragma unroll
                    for (int i = 0; i < 16; ++i)
                        xv[i] = __bfloat162float(A1[(size_t)((c * 28 + ih) * 28 + ow0 + i) * BATCH + b]);
#pragma unroll
                    for (int kw = 0; kw < 5; ++kw)
#pragma unroll
                        for (int i = 0; i < 5; ++i) {
                            float wv = ws[(((co0 + i) * 10 + c) * 5 + kh) * 5 + kw];
#pragma unroll
                            for (int j = 0; j < 12; ++j) acc[i][j] += wv * xv[kw + j];
                        }
                }
            }
#pragma unroll
            for (int i = 0; i < 5; ++i)
#pragma unroll
                for (int j = 0; j < 6; ++j)
                    res[i][j] = fmaxf(res[i][j], fmaxf(acc[i][2 * j], acc[i][2 * j + 1]));
        }
#pragma unroll
        for (int i = 0; i < 5; ++i)
#pragma unroll
            for (int j = 0; j < 6; ++j)
                P[(size_t)(((co0 + i) * 12 + poh) * 12 + h * 6 + j) * BATCH + b] = res[i][j];
    }
}

// ---------------- conv3 + permuted 1x1: P f32 [20][12][12][B] -> A4 f32 [1400][B] ----------------
__global__ __launch_bounds__(256, 2) void kC3(const float* __restrict__ P, const float* __restrict__ w,
                                              const float* __restrict__ bias, const float* __restrict__ pw,
                                              const float* __restrict__ pb, float* __restrict__ A4) {
    __shared__ float ws[5760];  // padded 32x20x9, zeros beyond 5220
    __shared__ float bs[32];
    __shared__ __hip_bfloat16 S[29][10][64];
    int tid = threadIdx.x;
    for (int i = tid; i < 5760; i += 256) ws[i] = (i < 5220) ? w[i] : 0.f;
    if (tid < 32) bs[tid] = (tid < 29) ? bias[tid] : 0.f;
    __syncthreads();
    int lane = tid & 63, g = tid >> 6;
    int b = blockIdx.x * 64 + lane;
    int oh = blockIdx.y;
    int co0 = g * 8;
    float acc[8][10];
#pragma unroll
    for (int i = 0; i < 8; ++i)
#pragma unroll
        for (int j = 0; j < 10; ++j) acc[i][j] = bs[co0 + i];
    for (int c = 0; c < 20; ++c) {
        for (int kh = 0; kh < 3; ++kh) {
            int ih = oh + kh;
            float xv[12];
#pragma unroll
            for (int i = 0; i < 12; ++i)
                xv[i] = P[(size_t)((c * 12 + ih) * 12 + i) * BATCH + b];
#pragma unroll
            for (int kw = 0; kw < 3; ++kw)
#pragma unroll
                for (int i = 0; i < 8; ++i) {
                    float wv = ws[((co0 + i) * 20 + c) * 9 + kh * 3 + kw];
#pragma unroll
                    for (int j = 0; j < 10; ++j) acc[i][j] += wv * xv[kw + j];
                }
        }
    }
#pragma unroll
    for (int i = 0; i < 8; ++i) {
        if (co0 + i < 29) {
#pragma unroll
            for (int j = 0; j < 10; ++j) S[co0 + i][j][lane] = __float2bfloat16(acc[i][j]);
        }
    }
    __syncthreads();
    // permuted per-channel 1x1 conv
    for (int t = g; t < 140; t += 4) {
        int i = t / 10, ow = t % 10;
        float v = pw[i * 3 + 0] * __bfloat162float(S[0][ow][lane]) +
                  pw[i * 3 + 1] * __bfloat162float(S[2 * i + 1][ow][lane]) +
                  pw[i * 3 + 2] * __bfloat162float(S[2 * i + 2][ow][lane]) + pb[i];
        A4[(size_t)(i * 100 + oh * 10 + ow) * BATCH + b] = v;
    }
}

// ---------------- fc1+fc2+fc3: A4 f32 [1400][B] -> out f32 [B][10] ----------------
__global__ __launch_bounds__(256) void kFC(const float* __restrict__ A4,
                                           const float* __restrict__ w1, const float* __restrict__ b1,
                                           const float* __restrict__ w2, const float* __restrict__ b2,
                                           const float* __restrict__ w3, const float* __restrict__ b3,
                                           float* __restrict__ out) {
    __shared__ float smem[7680];
    int tid = threadIdx.x, lane = tid & 31, g = tid >> 5;  // 8 groups x 32 batch lanes
    int b = blockIdx.x * 32 + lane;
    // ---- fc1: each group computes 15 of 120 outputs
    float acc[15];
#pragma unroll
    for (int j = 0; j < 15; ++j) acc[j] = b1[g * 15 + j];
    for (int k0 = 0; k0 < 1400; k0 += 64) {
        __syncthreads();
        for (int idx = tid; idx < 7680; idx += 256) {
            int co = idx >> 6, kk = idx & 63;
            int k = k0 + kk;
            smem[idx] = (k < 1400) ? w1[co * 1400 + k] : 0.f;
        }
        __syncthreads();
        int kc = min(64, 1400 - k0);
        for (int kk = 0; kk < kc; ++kk) {
            float a = A4[(size_t)(k0 + kk) * BATCH + b];
#pragma unroll
            for (int j = 0; j < 15; ++j) acc[j] += smem[(g * 15 + j) * 64 + kk] * a;
        }
    }
    __syncthreads();
#pragma unroll
    for (int j = 0; j < 15; ++j) smem[(g * 15 + j) * 32 + lane] = acc[j];  // F1 [120][32]
    __syncthreads();
    // ---- fc2: 84 outputs, 11 per group (clamped)
    float acc2[11];
#pragma unroll
    for (int j = 0; j < 11; ++j) acc2[j] = b2[min(g * 11 + j, 83)];
    for (int k = 0; k < 120; ++k) {
        float fa = smem[k * 32 + lane];
#pragma unroll
        for (int j = 0; j < 11; ++j) acc2[j] += w2[min(g * 11 + j, 83) * 120 + k] * fa;
    }
    __syncthreads();
#pragma unroll
    for (int j = 0; j < 11; ++j)
        if (g * 11 + j < 84) smem[3840 + (g * 11 + j) * 32 + lane] = acc2[j];  // F2 [84][32]
    __syncthreads();
    // ---- fc3: 10 outputs, 2 per group for g<5
    float acc3[2];
    int co0 = g * 2;
#pragma unroll
    for (int j = 0; j < 2; ++j) acc3[j] = b3[min(co0 + j, 9)];
    for (int k = 0; k < 84; ++k) {
        float fa = smem[3840 + k * 32 + lane];
#pragma unroll
        for (int j = 0; j < 2; ++j) acc3[j] += w3[min(co0 + j, 9) * 84 + k] * fa;
    }
    __syncthreads();
#pragma unroll
    for (int j = 0; j < 2; ++j)
        if (co0 + j < 10) smem[lane * 10 + co0 + j] = acc3[j];
    __syncthreads();
    for (int idx = tid; idx < 320; idx += 256) out[(size_t)blockIdx.x * 320 + idx] = smem[idx];
}

extern "C" void kernel_launch(void* const* d_in, const int* in_sizes, int n_in,
                              void* d_out, int out_size, void* d_ws, size_t ws_size,
                              hipStream_t stream) {
    const float* x   = (const float*)d_in[0];
    const float* w1  = (const float*)d_in[1];
    const float* b1  = (const float*)d_in[2];
    const float* w2  = (const float*)d_in[3];
    const float* b2  = (const float*)d_in[4];
    const float* w3  = (const float*)d_in[5];
    const float* b3  = (const float*)d_in[6];
    const float* pw  = (const float*)d_in[7];
    const float* pb  = (const float*)d_in[8];
    const float* f1w = (const float*)d_in[9];
    const float* f1b = (const float*)d_in[10];
    const float* f2w = (const float*)d_in[11];
    const float* f2b = (const float*)d_in[12];
    const float* f3w = (const float*)d_in[13];
    const float* f3b = (const float*)d_in[14];
    float* out = (float*)d_out;

    char* ws = (char*)d_ws;
    // region 0: X0 f32 [3072][B] (100663296 B), later reused for P f32 [2880][B] (94371840 B)
    // region 1: A1 bf16 [7840][B] (128450560 B), later reused for A4 f32 [1400][B] (45875200 B)
    float* X0 = (float*)ws;
    char* r1 = ws + 100663296;
    __hip_bfloat16* A1 = (__hip_bfloat16*)r1;
    float* P  = (float*)ws;
    float* A4 = (float*)r1;

    kT <<<dim3(48, 128),  256, 0, stream>>>(x, X0);
    kC1<<<dim3(128, 28),  256, 0, stream>>>(X0, w1, b1, A1);
    kC2<<<dim3(128, 12),  256, 0, stream>>>(A1, w2, b2, P);
    kC3<<<dim3(128, 10),  256, 0, stream>>>(P, w3, b3, pw, pb, A4);
    kFC<<<256,            256, 0, stream>>>(A4, f1w, f1b, f2w, f2b, f3w, f3b, out);
}

// Round 3
// 1019.395 us; speedup vs baseline: 1.3951x; 1.3951x over previous
//
#include <hip/hip_runtime.h>
#include <hip/hip_bf16.h>

#define BATCH 8192

typedef __attribute__((ext_vector_type(4))) short short4v;
typedef __attribute__((ext_vector_type(8))) short short8v;
typedef __attribute__((ext_vector_type(16))) float f32x16;

// ---------------- transpose: x f32 [B][3072] -> X0 f32 [3072][B] ----------------
__global__ __launch_bounds__(256) void kT(const float* __restrict__ x, float* __restrict__ X0) {
    __shared__ float t[64][65];
    int tx = threadIdx.x & 63, ty = threadIdx.x >> 6;
    int c0 = blockIdx.x * 64, b0 = blockIdx.y * 64;
#pragma unroll
    for (int r = 0; r < 16; ++r) {
        int i = ty + 4 * r;
        t[tx][i] = x[(size_t)(b0 + i) * 3072 + c0 + tx];
    }
    __syncthreads();
#pragma unroll
    for (int r = 0; r < 16; ++r) {
        int i = ty + 4 * r;
        X0[(size_t)(c0 + i) * BATCH + b0 + tx] = t[i][tx];
    }
}

// ---------------- conv1: X0 f32 [3][32][32][B] -> A1 bf16 [28h][512bg][28w][10c][16b] ----------------
__global__ __launch_bounds__(256) void kC1(const float* __restrict__ X0, const float* __restrict__ w,
                                           const float* __restrict__ bias, __hip_bfloat16* __restrict__ A1) {
    __shared__ float ws[750];
    __shared__ float bs[10];
    int tid = threadIdx.x;
    for (int i = tid; i < 750; i += 256) ws[i] = w[i];
    if (tid < 10) bs[tid] = bias[tid];
    __syncthreads();
    int lane = tid & 63, g = tid >> 6;
    int b = blockIdx.x * 64 + lane;
    int bg = blockIdx.x * 4 + (lane >> 4);
    int lb = lane & 15;
    int oh = blockIdx.y;
    int ow0 = g * 7;
    float acc[10][7];
#pragma unroll
    for (int co = 0; co < 10; ++co)
#pragma unroll
        for (int j = 0; j < 7; ++j) acc[co][j] = bs[co];
    for (int c = 0; c < 3; ++c) {
        for (int kh = 0; kh < 5; ++kh) {
            int ih = oh + kh;
            float xv[11];
#pragma unroll
            for (int i = 0; i < 11; ++i)
                xv[i] = X0[(size_t)((c * 32 + ih) * 32 + ow0 + i) * BATCH + b];
#pragma unroll
            for (int kw = 0; kw < 5; ++kw) {
#pragma unroll
                for (int co = 0; co < 10; ++co) {
                    float wv = ws[((co * 3 + c) * 5 + kh) * 5 + kw];
#pragma unroll
                    for (int j = 0; j < 7; ++j) acc[co][j] += wv * xv[kw + j];
                }
            }
        }
    }
#pragma unroll
    for (int co = 0; co < 10; ++co)
#pragma unroll
        for (int j = 0; j < 7; ++j)
            A1[(((size_t)oh * 512 + bg) * 28 + (ow0 + j)) * 160 + co * 16 + lb] = __float2bfloat16(acc[co][j]);
}

// ---------------- weight prep: w2 f32 OIHW [20][10][5][5] -> Wm bf16 [kh5][ks4][l64][8] ----------------
__global__ __launch_bounds__(256) void kWp(const float* __restrict__ w2, __hip_bfloat16* __restrict__ Wm) {
    int idx = blockIdx.x * 256 + threadIdx.x;  // < 1280
    int kh = idx >> 8;
    int rem = idx & 255;
    int ks = rem >> 6, l = rem & 63;
    int co = l & 31, g2 = l >> 5;
#pragma unroll
    for (int j = 0; j < 8; ++j) {
        int p = ks * 16 + g2 * 8 + j;  // phys k within the 64-wide window: (kw, c) = (p/10, p%10)
        float v = 0.f;
        if (co < 20 && p < 50) {
            int kw = p / 10, c = p % 10;
            v = w2[((co * 10 + c) * 5 + kh) * 5 + kw];
        }
        Wm[((size_t)(kh * 4 + ks) * 64 + l) * 8 + j] = __float2bfloat16(v);
    }
}

// ---------------- conv2 + pool via MFMA: A1 -> P f32 [20][12][12][B] ----------------
// block = (bgp of 32 batch, poh, half of ow); 384 thr = 6 waves, wave = 1 pooled col (2 ow x 2 oh)
__global__ __launch_bounds__(384) void kC2M(const __hip_bfloat16* __restrict__ A1,
                                            const __hip_bfloat16* __restrict__ Wm,
                                            const float* __restrict__ bias,
                                            float* __restrict__ P) {
    __shared__ char Xs[12 * 5904];  // 12 regions (6 ih x 2 bsub): [184 k-rows][16 b] bf16 + pad
    int tid = threadIdx.x;
    int bgp = blockIdx.x, poh = blockIdx.y, half = blockIdx.z;
    int iwlo = half ? 12 : 0;
    int niw = half ? 16 : 18;
    // stage: per region one contiguous slab of A1' (k-rows = iw*10+c naturally contiguous)
    int cpr = niw * 20;  // 16B chunks per region
    for (int t = tid; t < 12 * cpr; t += 384) {
        int reg = t / cpr;
        int off = (t - reg * cpr) * 16;
        int ihh = reg >> 1, bs = reg & 1;
        size_t srcoff = ((((size_t)(2 * poh + ihh) * 512) + bgp * 2 + bs) * 28 + iwlo) * 320 + off;
        *(short8v*)(Xs + reg * 5904 + off) = *(const short8v*)((const char*)A1 + srcoff);
    }
    // zero tail rows (k-window overrun reads must be finite; zero x zero-weight = 0)
    int tail0 = niw * 10;
    int tailw = 1476 - tail0 * 8;  // u32 words from first garbage row to end of region
    for (int t = tid; t < 12 * tailw; t += 384) {
        int reg = t / tailw, wd = t - reg * tailw;
        *(uint32_t*)(Xs + reg * 5904 + tail0 * 32 + wd * 4) = 0u;
    }
    __syncthreads();

    int lane = tid & 63, wv = tid >> 6;
    int g2 = lane >> 5, n16 = lane & 15, bsub = (lane >> 4) & 1;
    uint32_t xb = (uint32_t)(uint64_t)(void*)&Xs[0];

    f32x16 acc[2][2];  // [owl][r] -- static indices only (fully unrolled)
#pragma unroll
    for (int i = 0; i < 2; ++i)
#pragma unroll
        for (int j = 0; j < 2; ++j)
#pragma unroll
            for (int r = 0; r < 16; ++r) {
                int co = (r & 3) + 8 * (r >> 2) + 4 * g2;
                acc[i][j][r] = (co < 20) ? bias[co] : 0.f;
            }

    int owbase = 2 * wv;  // local ow
#pragma unroll
    for (int ks = 0; ks < 4; ++ks) {
        short8v a[5];
#pragma unroll
        for (int kh = 0; kh < 5; ++kh)
            a[kh] = *(const short8v*)(Wm + ((size_t)(kh * 4 + ks) * 64 + lane) * 8);
#pragma unroll
        for (int ihh = 0; ihh < 6; ++ihh) {
#pragma unroll
            for (int owl = 0; owl < 2; ++owl) {
                uint32_t addr = xb + (uint32_t)((ihh * 2 + bsub) * 5904 +
                                ((owbase + owl) * 10 + ks * 16 + g2 * 8) * 32 + n16 * 8);
                short4v r1, r2;
                asm volatile("ds_read_b64_tr_b16 %0, %1" : "=v"(r1) : "v"(addr));
                asm volatile("ds_read_b64_tr_b16 %0, %1 offset:128" : "=v"(r2) : "v"(addr));
                asm volatile("s_waitcnt lgkmcnt(0)");
                __builtin_amdgcn_sched_barrier(0);
                short8v b = __builtin_shufflevector(r1, r2, 0, 1, 2, 3, 4, 5, 6, 7);
#pragma unroll
                for (int rr = 0; rr < 2; ++rr) {
                    int kh = ihh - rr;
                    if (kh >= 0 && kh < 5)
                        acc[owl][rr] = __builtin_amdgcn_mfma_f32_32x32x16_bf16(a[kh], b, acc[owl][rr], 0, 0, 0);
                }
            }
        }
    }
    // pool 2x2 in registers + write P
    int pow = half * 6 + wv;
#pragma unroll
    for (int r = 0; r < 16; ++r) {
        int co = (r & 3) + 8 * (r >> 2) + 4 * g2;
        if (co < 20) {
            float v = fmaxf(fmaxf(acc[0][0][r], acc[0][1][r]), fmaxf(acc[1][0][r], acc[1][1][r]));
            P[(((size_t)co * 12 + poh) * 12 + pow) * BATCH + (size_t)bgp * 32 + bsub * 16 + n16] = v;
        }
    }
}

// ---------------- conv3 + permuted 1x1: P f32 [20][12][12][B] -> A4 f32 [1400][B] ----------------
__global__ __launch_bounds__(256, 2) void kC3(const float* __restrict__ P, const float* __restrict__ w,
                                              const float* __restrict__ bias, const float* __restrict__ pw,
                                              const float* __restrict__ pb, float* __restrict__ A4) {
    __shared__ float ws[5760];
    __shared__ float bs[32];
    __shared__ __hip_bfloat16 S[29][10][64];
    int tid = threadIdx.x;
    for (int i = tid; i < 5760; i += 256) ws[i] = (i < 5220) ? w[i] : 0.f;
    if (tid < 32) bs[tid] = (tid < 29) ? bias[tid] : 0.f;
    __syncthreads();
    int lane = tid & 63, g = tid >> 6;
    int b = blockIdx.x * 64 + lane;
    int oh = blockIdx.y;
    int co0 = g * 8;
    float acc[8][10];
#pragma unroll
    for (int i = 0; i < 8; ++i)
#pragma unroll
        for (int j = 0; j < 10; ++j) acc[i][j] = bs[co0 + i];
    for (int c = 0; c < 20; ++c) {
        for (int kh = 0; kh < 3; ++kh) {
            int ih = oh + kh;
            float xv[12];
#pragma unroll
            for (int i = 0; i < 12; ++i)
                xv[i] = P[(size_t)((c * 12 + ih) * 12 + i) * BATCH + b];
#pragma unroll
            for (int kw = 0; kw < 3; ++kw)
#pragma unroll
                for (int i = 0; i < 8; ++i) {
                    float wv = ws[((co0 + i) * 20 + c) * 9 + kh * 3 + kw];
#pragma unroll
                    for (int j = 0; j < 10; ++j) acc[i][j] += wv * xv[kw + j];
                }
        }
    }
#pragma unroll
    for (int i = 0; i < 8; ++i) {
        if (co0 + i < 29) {
#pragma unroll
            for (int j = 0; j < 10; ++j) S[co0 + i][j][lane] = __float2bfloat16(acc[i][j]);
        }
    }
    __syncthreads();
    for (int t = g; t < 140; t += 4) {
        int i = t / 10, ow = t % 10;
        float v = pw[i * 3 + 0] * __bfloat162float(S[0][ow][lane]) +
                  pw[i * 3 + 1] * __bfloat162float(S[2 * i + 1][ow][lane]) +
                  pw[i * 3 + 2] * __bfloat162float(S[2 * i + 2][ow][lane]) + pb[i];
        A4[(size_t)(i * 100 + oh * 10 + ow) * BATCH + b] = v;
    }
}

// ---------------- fc1+fc2+fc3: A4 f32 [1400][B] -> out f32 [B][10] ----------------
__global__ __launch_bounds__(256) void kFC(const float* __restrict__ A4,
                                           const float* __restrict__ w1, const float* __restrict__ b1,
                                           const float* __restrict__ w2, const float* __restrict__ b2,
                                           const float* __restrict__ w3, const float* __restrict__ b3,
                                           float* __restrict__ out) {
    __shared__ float smem[7680];
    int tid = threadIdx.x, lane = tid & 31, g = tid >> 5;
    int b = blockIdx.x * 32 + lane;
    float acc[15];
#pragma unroll
    for (int j = 0; j < 15; ++j) acc[j] = b1[g * 15 + j];
    for (int k0 = 0; k0 < 1400; k0 += 64) {
        __syncthreads();
        for (int idx = tid; idx < 7680; idx += 256) {
            int co = idx >> 6, kk = idx & 63;
            int k = k0 + kk;
            smem[idx] = (k < 1400) ? w1[co * 1400 + k] : 0.f;
        }
        __syncthreads();
        int kc = min(64, 1400 - k0);
        for (int kk = 0; kk < kc; ++kk) {
            float a = A4[(size_t)(k0 + kk) * BATCH + b];
#pragma unroll
            for (int j = 0; j < 15; ++j) acc[j] += smem[(g * 15 + j) * 64 + kk] * a;
        }
    }
    __syncthreads();
#pragma unroll
    for (int j = 0; j < 15; ++j) smem[(g * 15 + j) * 32 + lane] = acc[j];
    __syncthreads();
    float acc2[11];
#pragma unroll
    for (int j = 0; j < 11; ++j) acc2[j] = b2[min(g * 11 + j, 83)];
    for (int k = 0; k < 120; ++k) {
        float fa = smem[k * 32 + lane];
#pragma unroll
        for (int j = 0; j < 11; ++j) acc2[j] += w2[min(g * 11 + j, 83) * 120 + k] * fa;
    }
    __syncthreads();
#pragma unroll
    for (int j = 0; j < 11; ++j)
        if (g * 11 + j < 84) smem[3840 + (g * 11 + j) * 32 + lane] = acc2[j];
    __syncthreads();
    float acc3[2];
    int co0 = g * 2;
#pragma unroll
    for (int j = 0; j < 2; ++j) acc3[j] = b3[min(co0 + j, 9)];
    for (int k = 0; k < 84; ++k) {
        float fa = smem[3840 + k * 32 + lane];
#pragma unroll
        for (int j = 0; j < 2; ++j) acc3[j] += w3[min(co0 + j, 9) * 84 + k] * fa;
    }
    __syncthreads();
#pragma unroll
    for (int j = 0; j < 2; ++j)
        if (co0 + j < 10) smem[lane * 10 + co0 + j] = acc3[j];
    __syncthreads();
    for (int idx = tid; idx < 320; idx += 256) out[(size_t)blockIdx.x * 320 + idx] = smem[idx];
}

extern "C" void kernel_launch(void* const* d_in, const int* in_sizes, int n_in,
                              void* d_out, int out_size, void* d_ws, size_t ws_size,
                              hipStream_t stream) {
    const float* x   = (const float*)d_in[0];
    const float* w1  = (const float*)d_in[1];
    const float* b1  = (const float*)d_in[2];
    const float* w2  = (const float*)d_in[3];
    const float* b2  = (const float*)d_in[4];
    const float* w3  = (const float*)d_in[5];
    const float* b3  = (const float*)d_in[6];
    const float* pw  = (const float*)d_in[7];
    const float* pb  = (const float*)d_in[8];
    const float* f1w = (const float*)d_in[9];
    const float* f1b = (const float*)d_in[10];
    const float* f2w = (const float*)d_in[11];
    const float* f2b = (const float*)d_in[12];
    const float* f3w = (const float*)d_in[13];
    const float* f3b = (const float*)d_in[14];
    float* out = (float*)d_out;

    char* ws = (char*)d_ws;
    // region0 [0, 100663296): X0 f32 [3072][B]; later P f32 [2880][B] (94371840 B) + Wm (20 KB) in its tail
    // region1 [100663296, 229113856): A1' bf16 [28][512][28][10][16]; later A4 f32 [1400][B]
    float* X0 = (float*)ws;
    __hip_bfloat16* A1 = (__hip_bfloat16*)(ws + 100663296);
    float* P  = (float*)ws;
    __hip_bfloat16* Wm = (__hip_bfloat16*)(ws + 94371840);
    float* A4 = (float*)(ws + 100663296);

    kT  <<<dim3(48, 128),   256, 0, stream>>>(x, X0);
    kC1 <<<dim3(128, 28),   256, 0, stream>>>(X0, w1, b1, A1);
    kWp <<<5,               256, 0, stream>>>(w2, Wm);
    kC2M<<<dim3(256, 12, 2), 384, 0, stream>>>(A1, Wm, b2, P);
    kC3 <<<dim3(128, 10),   256, 0, stream>>>(P, w3, b3, pw, pb, A4);
    kFC <<<256,             256, 0, stream>>>(A4, f1w, f1b, f2w, f2b, f3w, f3b, out);
}

// Round 9
// 738.845 us; speedup vs baseline: 1.9248x; 1.3797x over previous
//
#include <hip/hip_runtime.h>
#include <hip/hip_bf16.h>

#define BATCH 8192

typedef __attribute__((ext_vector_type(4))) short short4v;
typedef __attribute__((ext_vector_type(8))) short short8v;
typedef __attribute__((ext_vector_type(16))) float f32x16;

__device__ inline float bf16val(float v) {
    return __bfloat162float(__float2bfloat16(v));
}

// ---------------- transpose: x f32 [B][3072] -> X0 f32 [3072][B] ----------------
__global__ __launch_bounds__(256) void kT(const float* __restrict__ x, float* __restrict__ X0) {
    __shared__ float t[64][65];
    int tx = threadIdx.x & 63, ty = threadIdx.x >> 6;
    int c0 = blockIdx.x * 64, b0 = blockIdx.y * 64;
#pragma unroll
    for (int r = 0; r < 16; ++r) {
        int i = ty + 4 * r;
        t[tx][i] = x[(size_t)(b0 + i) * 3072 + c0 + tx];
    }
    __syncthreads();
#pragma unroll
    for (int r = 0; r < 16; ++r) {
        int i = ty + 4 * r;
        X0[(size_t)(c0 + i) * BATCH + b0 + tx] = t[i][tx];
    }
}

// ---------------- conv1: X0 f32 [3][32][32][B] -> A1 bf16 [28h][512bg][28w][10c][16b] ----------------
__global__ __launch_bounds__(256) void kC1(const float* __restrict__ X0, const float* __restrict__ w,
                                           const float* __restrict__ bias, __hip_bfloat16* __restrict__ A1) {
    __shared__ float ws[750];
    __shared__ float bs[10];
    int tid = threadIdx.x;
    for (int i = tid; i < 750; i += 256) ws[i] = w[i];
    if (tid < 10) bs[tid] = bias[tid];
    __syncthreads();
    int lane = tid & 63, g = tid >> 6;
    int b = blockIdx.x * 64 + lane;
    int bg = blockIdx.x * 4 + (lane >> 4);
    int lb = lane & 15;
    int oh = blockIdx.y;
    int ow0 = g * 7;
    float acc[10][7];
#pragma unroll
    for (int co = 0; co < 10; ++co)
#pragma unroll
        for (int j = 0; j < 7; ++j) acc[co][j] = bs[co];
    for (int c = 0; c < 3; ++c) {
        for (int kh = 0; kh < 5; ++kh) {
            int ih = oh + kh;
            float xv[11];
#pragma unroll
            for (int i = 0; i < 11; ++i)
                xv[i] = X0[(size_t)((c * 32 + ih) * 32 + ow0 + i) * BATCH + b];
#pragma unroll
            for (int kw = 0; kw < 5; ++kw) {
#pragma unroll
                for (int co = 0; co < 10; ++co) {
                    float wv = ws[((co * 3 + c) * 5 + kh) * 5 + kw];
#pragma unroll
                    for (int j = 0; j < 7; ++j) acc[co][j] += wv * xv[kw + j];
                }
            }
        }
    }
#pragma unroll
    for (int co = 0; co < 10; ++co)
#pragma unroll
        for (int j = 0; j < 7; ++j)
            A1[(((size_t)oh * 512 + bg) * 28 + (ow0 + j)) * 160 + co * 16 + lb] = __float2bfloat16(acc[co][j]);
}

// ---------------- weight prep: w2 f32 OIHW [20][10][5][5] -> Wm bf16 [kh5][ks4][l64][8] ----------------
__global__ __launch_bounds__(256) void kWp(const float* __restrict__ w2, __hip_bfloat16* __restrict__ Wm) {
    int idx = blockIdx.x * 256 + threadIdx.x;  // < 1280
    int kh = idx >> 8;
    int rem = idx & 255;
    int ks = rem >> 6, l = rem & 63;
    int co = l & 31, g2 = l >> 5;
#pragma unroll
    for (int j = 0; j < 8; ++j) {
        int p = ks * 16 + g2 * 8 + j;
        float v = 0.f;
        if (co < 20 && p < 50) {
            int kw = p / 10, c = p % 10;
            v = w2[((co * 10 + c) * 5 + kh) * 5 + kw];
        }
        Wm[((size_t)(kh * 4 + ks) * 64 + l) * 8 + j] = __float2bfloat16(v);
    }
}

// ---------------- FC1 weight prep: f1w f32 [120][1400] -> hi/lo bf16 [cot4][ks88][l64][8] ----------------
// A-fragment layout identical to kWp (validated by kC2M): lane l: m=co=l&31, k=(l>>5)*8+j.
__global__ __launch_bounds__(256) void kWf(const float* __restrict__ f1w,
                                           __hip_bfloat16* __restrict__ W1hi, __hip_bfloat16* __restrict__ W1lo) {
    int id = blockIdx.x * 256 + threadIdx.x;
    if (id < 4 * 88 * 64) {
        int cot = id / (88 * 64), rem = id % (88 * 64);
        int ks = rem / 64, ll = rem % 64;
        int co = cot * 32 + (ll & 31);
#pragma unroll
        for (int j = 0; j < 8; ++j) {
            int k = ks * 16 + (ll >> 5) * 8 + j;
            float v = (co < 120 && k < 1400) ? f1w[co * 1400 + k] : 0.f;
            float hv = bf16val(v);
            W1hi[(size_t)id * 8 + j] = __float2bfloat16(v);
            W1lo[(size_t)id * 8 + j] = __float2bfloat16(v - hv);
        }
    }
}

// ---------------- conv2 + pool via MFMA: A1 -> P f32 [20][12][12][B] ----------------
__global__ __launch_bounds__(384) void kC2M(const __hip_bfloat16* __restrict__ A1,
                                            const __hip_bfloat16* __restrict__ Wm,
                                            const float* __restrict__ bias,
                                            float* __restrict__ P) {
    __shared__ char Xs[12 * 5904];
    int tid = threadIdx.x;
    int bgp = blockIdx.x, poh = blockIdx.y, half = blockIdx.z;
    int iwlo = half ? 12 : 0;
    int niw = half ? 16 : 18;
    int cpr = niw * 20;
    for (int t = tid; t < 12 * cpr; t += 384) {
        int reg = t / cpr;
        int off = (t - reg * cpr) * 16;
        int ihh = reg >> 1, bs = reg & 1;
        size_t srcoff = ((((size_t)(2 * poh + ihh) * 512) + bgp * 2 + bs) * 28 + iwlo) * 320 + off;
        *(short8v*)(Xs + reg * 5904 + off) = *(const short8v*)((const char*)A1 + srcoff);
    }
    int tail0 = niw * 10;
    int tailw = 1476 - tail0 * 8;
    for (int t = tid; t < 12 * tailw; t += 384) {
        int reg = t / tailw, wd = t - reg * tailw;
        *(uint32_t*)(Xs + reg * 5904 + tail0 * 32 + wd * 4) = 0u;
    }
    __syncthreads();

    int lane = tid & 63, wv = tid >> 6;
    int g2 = lane >> 5, n16 = lane & 15, bsub = (lane >> 4) & 1;
    uint32_t xb = (uint32_t)(uint64_t)(void*)&Xs[0];

    f32x16 acc[2][2];
#pragma unroll
    for (int i = 0; i < 2; ++i)
#pragma unroll
        for (int j = 0; j < 2; ++j)
#pragma unroll
            for (int r = 0; r < 16; ++r) {
                int co = (r & 3) + 8 * (r >> 2) + 4 * g2;
                acc[i][j][r] = (co < 20) ? bias[co] : 0.f;
            }

    int owbase = 2 * wv;
#pragma unroll
    for (int ks = 0; ks < 4; ++ks) {
        short8v a[5];
#pragma unroll
        for (int kh = 0; kh < 5; ++kh)
            a[kh] = *(const short8v*)(Wm + ((size_t)(kh * 4 + ks) * 64 + lane) * 8);
#pragma unroll
        for (int ihh = 0; ihh < 6; ++ihh) {
#pragma unroll
            for (int owl = 0; owl < 2; ++owl) {
                uint32_t addr = xb + (uint32_t)((ihh * 2 + bsub) * 5904 +
                                ((owbase + owl) * 10 + ks * 16 + g2 * 8) * 32 + n16 * 8);
                short4v r1, r2;
                asm volatile("ds_read_b64_tr_b16 %0, %1" : "=v"(r1) : "v"(addr));
                asm volatile("ds_read_b64_tr_b16 %0, %1 offset:128" : "=v"(r2) : "v"(addr));
                asm volatile("s_waitcnt lgkmcnt(0)");
                __builtin_amdgcn_sched_barrier(0);
                short8v b = __builtin_shufflevector(r1, r2, 0, 1, 2, 3, 4, 5, 6, 7);
#pragma unroll
                for (int rr = 0; rr < 2; ++rr) {
                    int kh = ihh - rr;
                    if (kh >= 0 && kh < 5)
                        acc[owl][rr] = __builtin_amdgcn_mfma_f32_32x32x16_bf16(a[kh], b, acc[owl][rr], 0, 0, 0);
                }
            }
        }
    }
    int pow = half * 6 + wv;
#pragma unroll
    for (int r = 0; r < 16; ++r) {
        int co = (r & 3) + 8 * (r >> 2) + 4 * g2;
        if (co < 20) {
            float v = fmaxf(fmaxf(acc[0][0][r], acc[0][1][r]), fmaxf(acc[1][0][r], acc[1][1][r]));
            P[(((size_t)co * 12 + poh) * 12 + pow) * BATCH + (size_t)bgp * 32 + bsub * 16 + n16] = v;
        }
    }
}

// ---------------- conv3 + permuted 1x1: P f32 [20][12][12][B] -> A4 f32 [1400][B] ----------------
__global__ __launch_bounds__(256, 2) void kC3(const float* __restrict__ P, const float* __restrict__ w,
                                              const float* __restrict__ bias, const float* __restrict__ pw,
                                              const float* __restrict__ pb, float* __restrict__ A4) {
    __shared__ float ws[5760];
    __shared__ float bs[32];
    __shared__ __hip_bfloat16 S[29][10][64];
    int tid = threadIdx.x;
    for (int i = tid; i < 5760; i += 256) ws[i] = (i < 5220) ? w[i] : 0.f;
    if (tid < 32) bs[tid] = (tid < 29) ? bias[tid] : 0.f;
    __syncthreads();
    int lane = tid & 63, g = tid >> 6;
    int b = blockIdx.x * 64 + lane;
    int oh = blockIdx.y;
    int co0 = g * 8;
    float acc[8][10];
#pragma unroll
    for (int i = 0; i < 8; ++i)
#pragma unroll
        for (int j = 0; j < 10; ++j) acc[i][j] = bs[co0 + i];
    for (int c = 0; c < 20; ++c) {
        for (int kh = 0; kh < 3; ++kh) {
            int ih = oh + kh;
            float xv[12];
#pragma unroll
            for (int i = 0; i < 12; ++i)
                xv[i] = P[(size_t)((c * 12 + ih) * 12 + i) * BATCH + b];
#pragma unroll
            for (int kw = 0; kw < 3; ++kw)
#pragma unroll
                for (int i = 0; i < 8; ++i) {
                    float wv = ws[((co0 + i) * 20 + c) * 9 + kh * 3 + kw];
#pragma unroll
                    for (int j = 0; j < 10; ++j) acc[i][j] += wv * xv[kw + j];
                }
        }
    }
#pragma unroll
    for (int i = 0; i < 8; ++i) {
        if (co0 + i < 29) {
#pragma unroll
            for (int j = 0; j < 10; ++j) S[co0 + i][j][lane] = __float2bfloat16(acc[i][j]);
        }
    }
    __syncthreads();
    for (int t = g; t < 140; t += 4) {
        int i = t / 10, ow = t % 10;
        float v = pw[i * 3 + 0] * __bfloat162float(S[0][ow][lane]) +
                  pw[i * 3 + 1] * __bfloat162float(S[2 * i + 1][ow][lane]) +
                  pw[i * 3 + 2] * __bfloat162float(S[2 * i + 2][ow][lane]) + pb[i];
        A4[(size_t)(i * 100 + oh * 10 + ow) * BATCH + b] = v;
    }
}

// ---------------- fused FC: fc1 via compensated-bf16 MFMA, fc2/fc3 via VALU (round-3 kFC code) ----------------
// grid 256 x 256 thr (4 waves), 32 batch per block.
// fc1: M=128 (120 pad), K=1408 (1400 pad); wave wv owns co tile [wv*32, wv*32+32).
// B staged in LDS as natural-order bf16 rows [n][k] (NO swizzle, NO packing):
//   row stride 136 elems = 272 B = 17x16B (b128-aligned every row, 4-way bank conflict, acceptable).
__global__ __launch_bounds__(256) void kFCM(const float* __restrict__ A4,
    const __hip_bfloat16* __restrict__ W1hi, const __hip_bfloat16* __restrict__ W1lo,
    const float* __restrict__ b1,
    const float* __restrict__ f2w, const float* __restrict__ b2,
    const float* __restrict__ w3, const float* __restrict__ b3,
    float* __restrict__ out)
{
    __shared__ __attribute__((aligned(16))) __hip_bfloat16 Bh[32][136];
    __shared__ __attribute__((aligned(16))) __hip_bfloat16 Bl[32][136];
    __shared__ float F1f[128 * 33];
    __shared__ float F2f[84 * 33];
    __shared__ float Ob[320];

    int tid = threadIdx.x;
    int l = tid & 63, wv = tid >> 6;
    int n = tid & 31, pp = tid >> 5;
    int g2 = l >> 5, nn = l & 31;
    int n0 = blockIdx.x * 32;

    f32x16 accA, accB, accC;
#pragma unroll
    for (int r = 0; r < 16; ++r) {
        int co = wv * 32 + (r & 3) + 8 * (r >> 2) + 4 * g2;
        accA[r] = (co < 120) ? b1[co] : 0.f;
        accB[r] = 0.f; accC[r] = 0.f;
    }

    for (int ch = 0; ch < 11; ++ch) {
        __syncthreads();
#pragma unroll
        for (int q = 0; q < 8; ++q) {
            int kp = q * 8 + pp;                 // 0..63: pair of k's
            int k = ch * 128 + kp * 2;
            float v0 = (k < 1400) ? A4[(size_t)k * BATCH + n0 + n] : 0.f;
            float v1 = (k + 1 < 1400) ? A4[(size_t)(k + 1) * BATCH + n0 + n] : 0.f;
            float h0 = bf16val(v0), h1 = bf16val(v1);
            Bh[n][2 * kp]     = __float2bfloat16(v0);
            Bh[n][2 * kp + 1] = __float2bfloat16(v1);
            Bl[n][2 * kp]     = __float2bfloat16(v0 - h0);
            Bl[n][2 * kp + 1] = __float2bfloat16(v1 - h1);
        }
        __syncthreads();
#pragma unroll
        for (int ks = 0; ks < 8; ++ks) {
            int ksg = ch * 8 + ks;
            short8v ahi = *(const short8v*)(W1hi + (((size_t)wv * 88 + ksg) * 64 + l) * 8);
            short8v alo = *(const short8v*)(W1lo + (((size_t)wv * 88 + ksg) * 64 + l) * 8);
            short8v bh = *(const short8v*)((const void*)&Bh[nn][ks * 16 + g2 * 8]);
            short8v bl = *(const short8v*)((const void*)&Bl[nn][ks * 16 + g2 * 8]);
            accA = __builtin_amdgcn_mfma_f32_32x32x16_bf16(ahi, bh, accA, 0, 0, 0);
            accB = __builtin_amdgcn_mfma_f32_32x32x16_bf16(ahi, bl, accB, 0, 0, 0);
            accC = __builtin_amdgcn_mfma_f32_32x32x16_bf16(alo, bh, accC, 0, 0, 0);
        }
    }
    // F1 -> LDS as plain f32 [co][nn] (no packing)
#pragma unroll
    for (int r = 0; r < 16; ++r) {
        int co = wv * 32 + (r & 3) + 8 * (r >> 2) + 4 * g2;
        F1f[co * 33 + nn] = accA[r] + accB[r] + accC[r];
    }
    __syncthreads();
    // ---- fc2: VALU, 11 outputs per pp-group (round-3 validated pattern)
    float acc2[11];
#pragma unroll
    for (int j = 0; j < 11; ++j) acc2[j] = b2[min(pp * 11 + j, 83)];
    for (int k = 0; k < 120; ++k) {
        float fa = F1f[k * 33 + n];
#pragma unroll
        for (int j = 0; j < 11; ++j) acc2[j] += f2w[min(pp * 11 + j, 83) * 120 + k] * fa;
    }
#pragma unroll
    for (int j = 0; j < 11; ++j)
        if (pp * 11 + j < 84) F2f[(pp * 11 + j) * 33 + n] = acc2[j];
    __syncthreads();
    // ---- fc3: VALU, 2 outputs per pp-group for pp<5
    float acc3[2];
    int co0 = pp * 2;
#pragma unroll
    for (int j = 0; j < 2; ++j) acc3[j] = b3[min(co0 + j, 9)];
    for (int k = 0; k < 84; ++k) {
        float fa = F2f[k * 33 + n];
#pragma unroll
        for (int j = 0; j < 2; ++j) acc3[j] += w3[min(co0 + j, 9) * 84 + k] * fa;
    }
#pragma unroll
    for (int j = 0; j < 2; ++j)
        if (co0 + j < 10) Ob[n * 10 + co0 + j] = acc3[j];
    __syncthreads();
    for (int idx = tid; idx < 320; idx += 256) out[(size_t)blockIdx.x * 320 + idx] = Ob[idx];
}

extern "C" void kernel_launch(void* const* d_in, const int* in_sizes, int n_in,
                              void* d_out, int out_size, void* d_ws, size_t ws_size,
                              hipStream_t stream) {
    const float* x   = (const float*)d_in[0];
    const float* w1  = (const float*)d_in[1];
    const float* b1  = (const float*)d_in[2];
    const float* w2  = (const float*)d_in[3];
    const float* b2  = (const float*)d_in[4];
    const float* w3  = (const float*)d_in[5];
    const float* b3  = (const float*)d_in[6];
    const float* pw  = (const float*)d_in[7];
    const float* pb  = (const float*)d_in[8];
    const float* f1w = (const float*)d_in[9];
    const float* f1b = (const float*)d_in[10];
    const float* f2w = (const float*)d_in[11];
    const float* f2b = (const float*)d_in[12];
    const float* f3w = (const float*)d_in[13];
    const float* f3b = (const float*)d_in[14];
    float* out = (float*)d_out;

    char* ws = (char*)d_ws;
    // region0 [0, 100663296): X0 f32 [3072][B] during kT/kC1; then P f32 [2880][B] ends 94371840,
    //   Wm at 94371840 (+20480), W1hi 94392320 (+360448), W1lo 94752768 (+360448) -> ends 95113216.
    // region1 [100663296, ...): A1' bf16 (128450560 B); later A4 f32 [1400][B] (45875200 B)
    float* X0 = (float*)ws;
    __hip_bfloat16* A1 = (__hip_bfloat16*)(ws + 100663296);
    float* P  = (float*)ws;
    __hip_bfloat16* Wm = (__hip_bfloat16*)(ws + 94371840);
    __hip_bfloat16* W1hi = (__hip_bfloat16*)(ws + 94392320);
    __hip_bfloat16* W1lo = (__hip_bfloat16*)(ws + 94752768);
    float* A4 = (float*)(ws + 100663296);

    kT  <<<dim3(48, 128),    256, 0, stream>>>(x, X0);
    kC1 <<<dim3(128, 28),    256, 0, stream>>>(X0, w1, b1, A1);
    kWp <<<5,                256, 0, stream>>>(w2, Wm);
    kWf <<<88,               256, 0, stream>>>(f1w, W1hi, W1lo);
    kC2M<<<dim3(256, 12, 2), 384, 0, stream>>>(A1, Wm, b2, P);
    kC3 <<<dim3(128, 10),    256, 0, stream>>>(P, w3, b3, pw, pb, A4);
    kFCM<<<256,              256, 0, stream>>>(A4, W1hi, W1lo, f1b, f2w, f2b, f3w, f3b, out);
}

// Round 10
// 729.526 us; speedup vs baseline: 1.9494x; 1.0128x over previous
//
#include <hip/hip_runtime.h>
#include <hip/hip_bf16.h>

#define BATCH 8192

typedef __attribute__((ext_vector_type(4))) short short4v;
typedef __attribute__((ext_vector_type(8))) short short8v;
typedef __attribute__((ext_vector_type(16))) float f32x16;

__device__ inline float bf16val(float v) {
    return __bfloat162float(__float2bfloat16(v));
}

// ---------------- transpose: x f32 [B][3072] -> X0 f32 [3072][B] ----------------
__global__ __launch_bounds__(256) void kT(const float* __restrict__ x, float* __restrict__ X0) {
    __shared__ float t[64][65];
    int tx = threadIdx.x & 63, ty = threadIdx.x >> 6;
    int c0 = blockIdx.x * 64, b0 = blockIdx.y * 64;
#pragma unroll
    for (int r = 0; r < 16; ++r) {
        int i = ty + 4 * r;
        t[tx][i] = x[(size_t)(b0 + i) * 3072 + c0 + tx];
    }
    __syncthreads();
#pragma unroll
    for (int r = 0; r < 16; ++r) {
        int i = ty + 4 * r;
        X0[(size_t)(c0 + i) * BATCH + b0 + tx] = t[i][tx];
    }
}

// ---------------- conv1: X0 f32 [3][32][32][B] -> A1 bf16 [28h][512bg][28w][10c][16b] ----------------
__global__ __launch_bounds__(256) void kC1(const float* __restrict__ X0, const float* __restrict__ w,
                                           const float* __restrict__ bias, __hip_bfloat16* __restrict__ A1) {
    __shared__ float ws[750];
    __shared__ float bs[10];
    int tid = threadIdx.x;
    for (int i = tid; i < 750; i += 256) ws[i] = w[i];
    if (tid < 10) bs[tid] = bias[tid];
    __syncthreads();
    int lane = tid & 63, g = tid >> 6;
    int b = blockIdx.x * 64 + lane;
    int bg = blockIdx.x * 4 + (lane >> 4);
    int lb = lane & 15;
    int oh = blockIdx.y;
    int ow0 = g * 7;
    float acc[10][7];
#pragma unroll
    for (int co = 0; co < 10; ++co)
#pragma unroll
        for (int j = 0; j < 7; ++j) acc[co][j] = bs[co];
    for (int c = 0; c < 3; ++c) {
        for (int kh = 0; kh < 5; ++kh) {
            int ih = oh + kh;
            float xv[11];
#pragma unroll
            for (int i = 0; i < 11; ++i)
                xv[i] = X0[(size_t)((c * 32 + ih) * 32 + ow0 + i) * BATCH + b];
#pragma unroll
            for (int kw = 0; kw < 5; ++kw) {
#pragma unroll
                for (int co = 0; co < 10; ++co) {
                    float wv = ws[((co * 3 + c) * 5 + kh) * 5 + kw];
#pragma unroll
                    for (int j = 0; j < 7; ++j) acc[co][j] += wv * xv[kw + j];
                }
            }
        }
    }
#pragma unroll
    for (int co = 0; co < 10; ++co)
#pragma unroll
        for (int j = 0; j < 7; ++j)
            A1[(((size_t)oh * 512 + bg) * 28 + (ow0 + j)) * 160 + co * 16 + lb] = __float2bfloat16(acc[co][j]);
}

// ---------------- weight prep: w2 f32 OIHW [20][10][5][5] -> Wm bf16 [kh5][ks4][l64][8] ----------------
__global__ __launch_bounds__(256) void kWp(const float* __restrict__ w2, __hip_bfloat16* __restrict__ Wm) {
    int idx = blockIdx.x * 256 + threadIdx.x;  // < 1280
    int kh = idx >> 8;
    int rem = idx & 255;
    int ks = rem >> 6, l = rem & 63;
    int co = l & 31, g2 = l >> 5;
#pragma unroll
    for (int j = 0; j < 8; ++j) {
        int p = ks * 16 + g2 * 8 + j;
        float v = 0.f;
        if (co < 20 && p < 50) {
            int kw = p / 10, c = p % 10;
            v = w2[((co * 10 + c) * 5 + kh) * 5 + kw];
        }
        Wm[((size_t)(kh * 4 + ks) * 64 + l) * 8 + j] = __float2bfloat16(v);
    }
}

// ---------------- FC1 weight prep: f1w f32 [120][1400] -> hi/lo bf16 [cot4][ks88][l64][8] ----------------
__global__ __launch_bounds__(256) void kWf(const float* __restrict__ f1w,
                                           __hip_bfloat16* __restrict__ W1hi, __hip_bfloat16* __restrict__ W1lo) {
    int id = blockIdx.x * 256 + threadIdx.x;
    if (id < 4 * 88 * 64) {
        int cot = id / (88 * 64), rem = id % (88 * 64);
        int ks = rem / 64, ll = rem % 64;
        int co = cot * 32 + (ll & 31);
#pragma unroll
        for (int j = 0; j < 8; ++j) {
            int k = ks * 16 + (ll >> 5) * 8 + j;
            float v = (co < 120 && k < 1400) ? f1w[co * 1400 + k] : 0.f;
            float hv = bf16val(v);
            W1hi[(size_t)id * 8 + j] = __float2bfloat16(v);
            W1lo[(size_t)id * 8 + j] = __float2bfloat16(v - hv);
        }
    }
}

// ---------------- conv2 + pool via MFMA: A1 -> P f32 [20][12][12][B] ----------------
// Inner loop: batched tr-reads (12 per group) + single lgkmcnt -- amortizes LDS latency
// 6x vs per-pair waits (round-9 profile: MfmaUtil 21%, latency-bound at 48 wait-points/wave).
__global__ __launch_bounds__(384) void kC2M(const __hip_bfloat16* __restrict__ A1,
                                            const __hip_bfloat16* __restrict__ Wm,
                                            const float* __restrict__ bias,
                                            float* __restrict__ P) {
    __shared__ char Xs[12 * 5904];
    int tid = threadIdx.x;
    int bgp = blockIdx.x, poh = blockIdx.y, half = blockIdx.z;
    int iwlo = half ? 12 : 0;
    int niw = half ? 16 : 18;
    int cpr = niw * 20;
    for (int t = tid; t < 12 * cpr; t += 384) {
        int reg = t / cpr;
        int off = (t - reg * cpr) * 16;
        int ihh = reg >> 1, bs = reg & 1;
        size_t srcoff = ((((size_t)(2 * poh + ihh) * 512) + bgp * 2 + bs) * 28 + iwlo) * 320 + off;
        *(short8v*)(Xs + reg * 5904 + off) = *(const short8v*)((const char*)A1 + srcoff);
    }
    int tail0 = niw * 10;
    int tailw = 1476 - tail0 * 8;
    for (int t = tid; t < 12 * tailw; t += 384) {
        int reg = t / tailw, wd = t - reg * tailw;
        *(uint32_t*)(Xs + reg * 5904 + tail0 * 32 + wd * 4) = 0u;
    }
    __syncthreads();

    int lane = tid & 63, wv = tid >> 6;
    int g2 = lane >> 5, n16 = lane & 15, bsub = (lane >> 4) & 1;
    uint32_t xb = (uint32_t)(uint64_t)(void*)&Xs[0];

    f32x16 acc[2][2];
#pragma unroll
    for (int i = 0; i < 2; ++i)
#pragma unroll
        for (int j = 0; j < 2; ++j)
#pragma unroll
            for (int r = 0; r < 16; ++r) {
                int co = (r & 3) + 8 * (r >> 2) + 4 * g2;
                acc[i][j][r] = (co < 20) ? bias[co] : 0.f;
            }

    int owbase = 2 * wv;
#pragma unroll
    for (int ks = 0; ks < 4; ++ks) {
        short8v a[5];
#pragma unroll
        for (int kh = 0; kh < 5; ++kh)
            a[kh] = *(const short8v*)(Wm + ((size_t)(kh * 4 + ks) * 64 + lane) * 8);
#pragma unroll
        for (int grp = 0; grp < 2; ++grp) {  // ihh in [3*grp, 3*grp+3)
            short4v r1[6], r2[6];
#pragma unroll
            for (int ii = 0; ii < 3; ++ii) {
#pragma unroll
                for (int owl = 0; owl < 2; ++owl) {
                    int ihh = grp * 3 + ii;
                    uint32_t addr = xb + (uint32_t)((ihh * 2 + bsub) * 5904 +
                                    ((owbase + owl) * 10 + ks * 16 + g2 * 8) * 32 + n16 * 8);
                    asm volatile("ds_read_b64_tr_b16 %0, %1" : "=v"(r1[ii * 2 + owl]) : "v"(addr));
                    asm volatile("ds_read_b64_tr_b16 %0, %1 offset:128" : "=v"(r2[ii * 2 + owl]) : "v"(addr));
                }
            }
            asm volatile("s_waitcnt lgkmcnt(0)");
            __builtin_amdgcn_sched_barrier(0);
#pragma unroll
            for (int ii = 0; ii < 3; ++ii) {
#pragma unroll
                for (int owl = 0; owl < 2; ++owl) {
                    int ihh = grp * 3 + ii;
                    short8v b = __builtin_shufflevector(r1[ii * 2 + owl], r2[ii * 2 + owl],
                                                        0, 1, 2, 3, 4, 5, 6, 7);
#pragma unroll
                    for (int rr = 0; rr < 2; ++rr) {
                        int kh = ihh - rr;
                        if (kh >= 0 && kh < 5)
                            acc[owl][rr] = __builtin_amdgcn_mfma_f32_32x32x16_bf16(a[kh], b, acc[owl][rr], 0, 0, 0);
                    }
                }
            }
        }
    }
    int pow = half * 6 + wv;
#pragma unroll
    for (int r = 0; r < 16; ++r) {
        int co = (r & 3) + 8 * (r >> 2) + 4 * g2;
        if (co < 20) {
            float v = fmaxf(fmaxf(acc[0][0][r], acc[0][1][r]), fmaxf(acc[1][0][r], acc[1][1][r]));
            P[(((size_t)co * 12 + poh) * 12 + pow) * BATCH + (size_t)bgp * 32 + bsub * 16 + n16] = v;
        }
    }
}

// ---------------- conv3 + permuted 1x1: P f32 [20][12][12][B] -> A4 f32 [1400][B] ----------------
__global__ __launch_bounds__(256, 2) void kC3(const float* __restrict__ P, const float* __restrict__ w,
                                              const float* __restrict__ bias, const float* __restrict__ pw,
                                              const float* __restrict__ pb, float* __restrict__ A4) {
    __shared__ float ws[5760];
    __shared__ float bs[32];
    __shared__ __hip_bfloat16 S[29][10][64];
    int tid = threadIdx.x;
    for (int i = tid; i < 5760; i += 256) ws[i] = (i < 5220) ? w[i] : 0.f;
    if (tid < 32) bs[tid] = (tid < 29) ? bias[tid] : 0.f;
    __syncthreads();
    int lane = tid & 63, g = tid >> 6;
    int b = blockIdx.x * 64 + lane;
    int oh = blockIdx.y;
    int co0 = g * 8;
    float acc[8][10];
#pragma unroll
    for (int i = 0; i < 8; ++i)
#pragma unroll
        for (int j = 0; j < 10; ++j) acc[i][j] = bs[co0 + i];
    for (int c = 0; c < 20; ++c) {
        for (int kh = 0; kh < 3; ++kh) {
            int ih = oh + kh;
            float xv[12];
#pragma unroll
            for (int i = 0; i < 12; ++i)
                xv[i] = P[(size_t)((c * 12 + ih) * 12 + i) * BATCH + b];
#pragma unroll
            for (int kw = 0; kw < 3; ++kw)
#pragma unroll
                for (int i = 0; i < 8; ++i) {
                    float wv = ws[((co0 + i) * 20 + c) * 9 + kh * 3 + kw];
#pragma unroll
                    for (int j = 0; j < 10; ++j) acc[i][j] += wv * xv[kw + j];
                }
        }
    }
#pragma unroll
    for (int i = 0; i < 8; ++i) {
        if (co0 + i < 29) {
#pragma unroll
            for (int j = 0; j < 10; ++j) S[co0 + i][j][lane] = __float2bfloat16(acc[i][j]);
        }
    }
    __syncthreads();
    for (int t = g; t < 140; t += 4) {
        int i = t / 10, ow = t % 10;
        float v = pw[i * 3 + 0] * __bfloat162float(S[0][ow][lane]) +
                  pw[i * 3 + 1] * __bfloat162float(S[2 * i + 1][ow][lane]) +
                  pw[i * 3 + 2] * __bfloat162float(S[2 * i + 2][ow][lane]) + pb[i];
        A4[(size_t)(i * 100 + oh * 10 + ow) * BATCH + b] = v;
    }
}

// ---------------- fused FC: fc1 via compensated-bf16 MFMA, fc2/fc3 via VALU ----------------
__global__ __launch_bounds__(256) void kFCM(const float* __restrict__ A4,
    const __hip_bfloat16* __restrict__ W1hi, const __hip_bfloat16* __restrict__ W1lo,
    const float* __restrict__ b1,
    const float* __restrict__ f2w, const float* __restrict__ b2,
    const float* __restrict__ w3, const float* __restrict__ b3,
    float* __restrict__ out)
{
    __shared__ __attribute__((aligned(16))) __hip_bfloat16 Bh[32][136];
    __shared__ __attribute__((aligned(16))) __hip_bfloat16 Bl[32][136];
    __shared__ float F1f[128 * 33];
    __shared__ float F2f[84 * 33];
    __shared__ float Ob[320];

    int tid = threadIdx.x;
    int l = tid & 63, wv = tid >> 6;
    int n = tid & 31, pp = tid >> 5;
    int g2 = l >> 5, nn = l & 31;
    int n0 = blockIdx.x * 32;

    f32x16 accA, accB, accC;
#pragma unroll
    for (int r = 0; r < 16; ++r) {
        int co = wv * 32 + (r & 3) + 8 * (r >> 2) + 4 * g2;
        accA[r] = (co < 120) ? b1[co] : 0.f;
        accB[r] = 0.f; accC[r] = 0.f;
    }

    for (int ch = 0; ch < 11; ++ch) {
        __syncthreads();
#pragma unroll
        for (int q = 0; q < 8; ++q) {
            int kp = q * 8 + pp;
            int k = ch * 128 + kp * 2;
            float v0 = (k < 1400) ? A4[(size_t)k * BATCH + n0 + n] : 0.f;
            float v1 = (k + 1 < 1400) ? A4[(size_t)(k + 1) * BATCH + n0 + n] : 0.f;
            float h0 = bf16val(v0), h1 = bf16val(v1);
            Bh[n][2 * kp]     = __float2bfloat16(v0);
            Bh[n][2 * kp + 1] = __float2bfloat16(v1);
            Bl[n][2 * kp]     = __float2bfloat16(v0 - h0);
            Bl[n][2 * kp + 1] = __float2bfloat16(v1 - h1);
        }
        __syncthreads();
#pragma unroll
        for (int ks = 0; ks < 8; ++ks) {
            int ksg = ch * 8 + ks;
            short8v ahi = *(const short8v*)(W1hi + (((size_t)wv * 88 + ksg) * 64 + l) * 8);
            short8v alo = *(const short8v*)(W1lo + (((size_t)wv * 88 + ksg) * 64 + l) * 8);
            short8v bh = *(const short8v*)((const void*)&Bh[nn][ks * 16 + g2 * 8]);
            short8v bl = *(const short8v*)((const void*)&Bl[nn][ks * 16 + g2 * 8]);
            accA = __builtin_amdgcn_mfma_f32_32x32x16_bf16(ahi, bh, accA, 0, 0, 0);
            accB = __builtin_amdgcn_mfma_f32_32x32x16_bf16(ahi, bl, accB, 0, 0, 0);
            accC = __builtin_amdgcn_mfma_f32_32x32x16_bf16(alo, bh, accC, 0, 0, 0);
        }
    }
#pragma unroll
    for (int r = 0; r < 16; ++r) {
        int co = wv * 32 + (r & 3) + 8 * (r >> 2) + 4 * g2;
        F1f[co * 33 + nn] = accA[r] + accB[r] + accC[r];
    }
    __syncthreads();
    float acc2[11];
#pragma unroll
    for (int j = 0; j < 11; ++j) acc2[j] = b2[min(pp * 11 + j, 83)];
    for (int k = 0; k < 120; ++k) {
        float fa = F1f[k * 33 + n];
#pragma unroll
        for (int j = 0; j < 11; ++j) acc2[j] += f2w[min(pp * 11 + j, 83) * 120 + k] * fa;
    }
#pragma unroll
    for (int j = 0; j < 11; ++j)
        if (pp * 11 + j < 84) F2f[(pp * 11 + j) * 33 + n] = acc2[j];
    __syncthreads();
    float acc3[2];
    int co0 = pp * 2;
#pragma unroll
    for (int j = 0; j < 2; ++j) acc3[j] = b3[min(co0 + j, 9)];
    for (int k = 0; k < 84; ++k) {
        float fa = F2f[k * 33 + n];
#pragma unroll
        for (int j = 0; j < 2; ++j) acc3[j] += w3[min(co0 + j, 9) * 84 + k] * fa;
    }
#pragma unroll
    for (int j = 0; j < 2; ++j)
        if (co0 + j < 10) Ob[n * 10 + co0 + j] = acc3[j];
    __syncthreads();
    for (int idx = tid; idx < 320; idx += 256) out[(size_t)blockIdx.x * 320 + idx] = Ob[idx];
}

extern "C" void kernel_launch(void* const* d_in, const int* in_sizes, int n_in,
                              void* d_out, int out_size, void* d_ws, size_t ws_size,
                              hipStream_t stream) {
    const float* x   = (const float*)d_in[0];
    const float* w1  = (const float*)d_in[1];
    const float* b1  = (const float*)d_in[2];
    const float* w2  = (const float*)d_in[3];
    const float* b2  = (const float*)d_in[4];
    const float* w3  = (const float*)d_in[5];
    const float* b3  = (const float*)d_in[6];
    const float* pw  = (const float*)d_in[7];
    const float* pb  = (const float*)d_in[8];
    const float* f1w = (const float*)d_in[9];
    const float* f1b = (const float*)d_in[10];
    const float* f2w = (const float*)d_in[11];
    const float* f2b = (const float*)d_in[12];
    const float* f3w = (const float*)d_in[13];
    const float* f3b = (const float*)d_in[14];
    float* out = (float*)d_out;

    char* ws = (char*)d_ws;
    // region0 [0, 100663296): X0 f32 [3072][B] during kT/kC1; then P f32 [2880][B] ends 94371840,
    //   Wm at 94371840 (+20480), W1hi 94392320 (+360448), W1lo 94752768 (+360448) -> ends 95113216.
    // region1 [100663296, ...): A1' bf16 (128450560 B); later A4 f32 [1400][B] (45875200 B)
    float* X0 = (float*)ws;
    __hip_bfloat16* A1 = (__hip_bfloat16*)(ws + 100663296);
    float* P  = (float*)ws;
    __hip_bfloat16* Wm = (__hip_bfloat16*)(ws + 94371840);
    __hip_bfloat16* W1hi = (__hip_bfloat16*)(ws + 94392320);
    __hip_bfloat16* W1lo = (__hip_bfloat16*)(ws + 94752768);
    float* A4 = (float*)(ws + 100663296);

    kT  <<<dim3(48, 128),    256, 0, stream>>>(x, X0);
    kC1 <<<dim3(128, 28),    256, 0, stream>>>(X0, w1, b1, A1);
    kWp <<<5,                256, 0, stream>>>(w2, Wm);
    kWf <<<88,               256, 0, stream>>>(f1w, W1hi, W1lo);
    kC2M<<<dim3(256, 12, 2), 384, 0, stream>>>(A1, Wm, b2, P);
    kC3 <<<dim3(128, 10),    256, 0, stream>>>(P, w3, b3, pw, pb, A4);
    kFCM<<<256,              256, 0, stream>>>(A4, W1hi, W1lo, f1b, f2w, f2b, f3w, f3b, out);
}